// Round 6
// baseline (173.982 us; speedup 1.0000x reference)
//
#include <hip/hip_runtime.h>

#define DI __device__ __forceinline__

using f32x4  = __attribute__((ext_vector_type(4))) float;
using bf16x8 = __attribute__((ext_vector_type(8))) __bf16;
using u16x4  = __attribute__((ext_vector_type(4))) unsigned short;
using u32x4  = __attribute__((ext_vector_type(4))) unsigned int;

constexpr int NNODE = 8192;

DI unsigned short f2bf(float f) {
    unsigned int u = __builtin_bit_cast(unsigned int, f);
    u += 0x7fffu + ((u >> 16) & 1u);   // round-to-nearest-even
    return (unsigned short)(u >> 16);
}
DI float bf2f(unsigned short s) {
    return __builtin_bit_cast(float, (unsigned int)s << 16);
}

// raw barrier: does NOT drain vmcnt (unlike __syncthreads), so prefetch loads
// stay in flight across it. lgkmcnt(0) before it makes our ds_writes visible;
// trailing memory clobber pins the next iteration's ds_reads after it.
DI void lbar() {
    asm volatile("s_waitcnt lgkmcnt(0)" ::: "memory");
    __builtin_amdgcn_s_barrier();
    asm volatile("" ::: "memory");
}

// swizzled LDS byte offsets (G4: break row-stride bank conflicts)
DI int swz256(int r, int cb) { return r * 256 + (cb ^ ((r & 15) << 4)); } // 256B rows (K=128 bf16)
DI int swz128(int r, int cb) { return r * 128 + (cb ^ ((r & 7) << 4)); }  // 128B rows (K=64 bf16)

// ---------------- weight prep: transpose to [n][k], split into bf16 hi/lo ----------------
__global__ void prep_w(const float* __restrict__ W_emb, const float* __restrict__ W_e,
                       const float* __restrict__ W_gc1, const float* __restrict__ W_gc2,
                       unsigned short* __restrict__ WembT_hi, unsigned short* __restrict__ WembT_lo,
                       unsigned short* __restrict__ WcatT_hi, unsigned short* __restrict__ WcatT_lo,
                       unsigned short* __restrict__ Wg2T_hi, unsigned short* __restrict__ Wg2T_lo)
{
    int gid = blockIdx.x * 256 + threadIdx.x;
    if (gid >= 576 * 128) return;
    int k = gid & 127, n = gid >> 7;
    float v;
    unsigned short *dh, *dl;
    if (n < 128) {                       // W_emb^T
        v = W_emb[k * 128 + n];
        dh = WembT_hi + n * 128 + k; dl = WembT_lo + n * 128 + k;
    } else if (n < 512) {                // [W_e_src | W_e_dst | W_gc1]^T
        int m = n - 128;
        if (m < 128)      v = W_e[k * 128 + m];
        else if (m < 256) v = W_e[(k + 128) * 128 + (m - 128)];
        else              v = W_gc1[k * 128 + (m - 256)];
        dh = WcatT_hi + m * 128 + k; dl = WcatT_lo + m * 128 + k;
    } else {                             // W_gc2^T padded 40 -> 64
        int c = n - 512;
        v = (c < 40) ? W_gc2[k * 40 + c] : 0.f;
        dh = Wg2T_hi + c * 128 + k; dl = Wg2T_lo + c * 128 + k;
    }
    unsigned short hi = f2bf(v);
    *dh = hi;
    *dl = f2bf(v - bf2f(hi));
}

// ---------------- fused: h = x@W_emb+b_emb ; [s_src | s_dst^T | g1^T] = h@W_cat ----------------
__global__ __launch_bounds__(512) void gemm_hs(
    const float* __restrict__ x,
    const unsigned short* __restrict__ WembT_hi, const unsigned short* __restrict__ WembT_lo,
    const unsigned short* __restrict__ WcatT_hi, const unsigned short* __restrict__ WcatT_lo,
    const float* __restrict__ b_emb,
    float* __restrict__ out_s,              // s_src [8192][128] fp32
    unsigned short* __restrict__ out_t)     // B_A: [256][8192] bf16 (s_dst | g1 transposed)
{
    __shared__ unsigned short Hh[64 * 128], Hl[64 * 128];
    char* Hhc = (char*)Hh; char* Hlc = (char*)Hl;

    const int tid = threadIdx.x;
    const int r0 = blockIdx.x * 64;
    const int lane = tid & 63, wid = tid >> 6;
    const int lrow = lane & 15, lk8 = (lane >> 4) * 8, lkb = (lane >> 4) * 16;
    const int wrg = wid & 3;        // row group (16 rows)
    const int wcg = wid >> 2;       // col group

    // ---- stage x (fp32 -> hi/lo bf16) into LDS ----
    #pragma unroll
    for (int p = 0; p < 4; ++p) {
        int idx = tid + 512 * p, r = idx >> 5, c4 = idx & 31;
        f32x4 v = *(const f32x4*)(x + (size_t)(r0 + r) * 128 + c4 * 4);
        u16x4 ph, pl;
        #pragma unroll
        for (int j = 0; j < 4; ++j) {
            unsigned short hi = f2bf(v[j]);
            ph[j] = hi; pl[j] = f2bf(v[j] - bf2f(hi));
        }
        *(u16x4*)(Hhc + swz256(r, c4 * 8)) = ph;
        *(u16x4*)(Hlc + swz256(r, c4 * 8)) = pl;
    }
    __syncthreads();

    // ---- phase 1: h(16 rows x 64 cols per wave) = x @ W_emb ----
    f32x4 acc[4];
    #pragma unroll
    for (int i = 0; i < 4; ++i) acc[i] = f32x4{0.f, 0.f, 0.f, 0.f};
    const int arow = wrg * 16 + lrow;
    #pragma unroll
    for (int kk = 0; kk < 4; ++kk) {
        bf16x8 ah = *(const bf16x8*)(Hhc + swz256(arow, kk * 64 + lkb));
        bf16x8 al = *(const bf16x8*)(Hlc + swz256(arow, kk * 64 + lkb));
        #pragma unroll
        for (int nf = 0; nf < 4; ++nf) {
            const int n = wcg * 64 + nf * 16 + lrow;
            bf16x8 bh = *(const bf16x8*)(WembT_hi + (size_t)n * 128 + kk * 32 + lk8);
            bf16x8 bl = *(const bf16x8*)(WembT_lo + (size_t)n * 128 + kk * 32 + lk8);
            acc[nf] = __builtin_amdgcn_mfma_f32_16x16x32_bf16(ah, bh, acc[nf], 0, 0, 0);
            acc[nf] = __builtin_amdgcn_mfma_f32_16x16x32_bf16(ah, bl, acc[nf], 0, 0, 0);
            acc[nf] = __builtin_amdgcn_mfma_f32_16x16x32_bf16(al, bh, acc[nf], 0, 0, 0);
        }
    }
    __syncthreads();   // all phase-1 reads of x done; LDS can be overwritten with h

    // ---- write h (+b_emb) hi/lo into LDS (same swizzled layout) ----
    #pragma unroll
    for (int nf = 0; nf < 4; ++nf) {
        const int col = wcg * 64 + nf * 16 + lrow;
        const float bv = b_emb[col];
        #pragma unroll
        for (int j = 0; j < 4; ++j) {
            const int row = wrg * 16 + ((lane >> 4) << 2) + j;
            float v = acc[nf][j] + bv;
            unsigned short hi = f2bf(v);
            *(unsigned short*)(Hhc + swz256(row, col * 2)) = hi;
            *(unsigned short*)(Hlc + swz256(row, col * 2)) = f2bf(v - bf2f(hi));
        }
    }
    __syncthreads();

    // ---- phase 2: [s_src | s_dst^T | g1^T] = h @ W_cat (wave: 16 rows x 192 cols) ----
    f32x4 acc2[12];
    #pragma unroll
    for (int i = 0; i < 12; ++i) acc2[i] = f32x4{0.f, 0.f, 0.f, 0.f};
    #pragma unroll
    for (int kk = 0; kk < 4; ++kk) {
        bf16x8 ah = *(const bf16x8*)(Hhc + swz256(arow, kk * 64 + lkb));
        bf16x8 al = *(const bf16x8*)(Hlc + swz256(arow, kk * 64 + lkb));
        #pragma unroll
        for (int nf = 0; nf < 12; ++nf) {
            const int n = wcg * 192 + nf * 16 + lrow;
            bf16x8 bh = *(const bf16x8*)(WcatT_hi + (size_t)n * 128 + kk * 32 + lk8);
            bf16x8 bl = *(const bf16x8*)(WcatT_lo + (size_t)n * 128 + kk * 32 + lk8);
            acc2[nf] = __builtin_amdgcn_mfma_f32_16x16x32_bf16(ah, bh, acc2[nf], 0, 0, 0);
            acc2[nf] = __builtin_amdgcn_mfma_f32_16x16x32_bf16(ah, bl, acc2[nf], 0, 0, 0);
            acc2[nf] = __builtin_amdgcn_mfma_f32_16x16x32_bf16(al, bh, acc2[nf], 0, 0, 0);
        }
    }
    const int rowb = r0 + wrg * 16 + ((lane >> 4) << 2);
    #pragma unroll
    for (int nf = 0; nf < 12; ++nf) {
        const int col = wcg * 192 + nf * 16 + lrow;
        if (wcg == 0 && nf < 8) {            // cols 0..127 -> s_src fp32 row-major
            #pragma unroll
            for (int j = 0; j < 4; ++j)
                out_s[(size_t)(rowb + j) * 128 + col] = acc2[nf][j];
        } else {                              // cols 128..383 -> bf16 transposed
            u16x4 pk = { f2bf(acc2[nf][0]), f2bf(acc2[nf][1]), f2bf(acc2[nf][2]), f2bf(acc2[nf][3]) };
            *(u16x4*)(out_t + (size_t)(col - 128) * NNODE + rowb) = pk;
        }
    }
}

// ---------------- big adj GEMM, counted-vmcnt 2-deep pipeline ----------------
// T[i][n] = sum_j adj[i][j] * Bt[n][j].
// Two register sets R0/R1 hold tiles t+1, t+2 in flight; raw s_barrier (lbar)
// never drains vmcnt, so the compiler's dependency waitcnt before each ds_write
// is COUNTED (vmcnt(6)), not a drain -> HBM latency hidden across tiles.
template<int NCOLS, int KSPLIT, bool DEG, bool REV>
__global__ __launch_bounds__(512) void adj_gemm(
    const float* __restrict__ adj,
    const unsigned short* __restrict__ Bt,   // [NCOLS][8192] bf16
    float* __restrict__ Tpart,               // [KSPLIT][8192][NCOLS] fp32
    float* __restrict__ degp)                // [KSPLIT][8192] partial row sums
{
    __shared__ unsigned short A_lds[2][64 * 64];
    __shared__ unsigned short B_lds[2][NCOLS * 64];

    const int tid = threadIdx.x;
    const int r0 = blockIdx.x * 64;
    const int ks = blockIdx.y;
    constexpr int KLEN = NNODE / KSPLIT;
    constexpr int NT = KLEN / 64;            // even
    const int kbase = ks * KLEN;

    constexpr int NB = NCOLS / 64;           // 16B B-chunks per thread per tile
    struct Regs { f32x4 a[2]; u32x4 b[NB]; };
    Regs R0, R1;
    float dsum0 = 0.f, dsum1 = 0.f;
    const int ar0 = tid >> 4, ac4 = tid & 15;

    const int lane = tid & 63, wid = tid >> 6;
    constexpr int FM = (NCOLS == 256) ? 2 : 1;
    constexpr int FN = (NCOLS == 256) ? 4 : 2;
    const int wr = (NCOLS == 256) ? (wid >> 2) : (wid >> 1);
    const int wc = (NCOLS == 256) ? (wid & 3) : (wid & 1);
    const int row_w = wr * FM * 16, col_w = wc * FN * 16;
    const int lrow = lane & 15, lkb = (lane >> 4) * 16;

    f32x4 acc[FM][FN];
    #pragma unroll
    for (int fm = 0; fm < FM; ++fm)
        #pragma unroll
        for (int fn = 0; fn < FN; ++fn) acc[fm][fn] = f32x4{0.f, 0.f, 0.f, 0.f};

    auto order = [&](int tt) { return REV ? (NT - 1 - tt) : tt; };

    // issue loads only -- never touch the values here (no forced wait)
    auto loadG = [&](int t, Regs& R) {
        const int kt = kbase + order(t) * 64;
        #pragma unroll
        for (int p = 0; p < 2; ++p)
            R.a[p] = *(const f32x4*)(adj + (size_t)(r0 + ar0 + 32 * p) * NNODE + kt + ac4 * 4);
        #pragma unroll
        for (int p = 0; p < NB; ++p) {
            const int idx = tid + 512 * p, n = idx >> 3, c = idx & 7;
            R.b[p] = *(const u32x4*)(Bt + (size_t)n * NNODE + kt + c * 8);
        }
    };
    // consume values: convert, deg-sum, ds_write (compiler emits counted vmcnt here)
    auto storeL = [&](int buf, Regs& R) {
        char* Ac = (char*)(A_lds[buf]);
        char* Bc = (char*)(B_lds[buf]);
        #pragma unroll
        for (int p = 0; p < 2; ++p) {
            if (DEG) {
                float s = R.a[p][0] + R.a[p][1] + R.a[p][2] + R.a[p][3];
                if (p == 0) dsum0 += s; else dsum1 += s;
            }
            u16x4 pk = { f2bf(R.a[p][0]), f2bf(R.a[p][1]), f2bf(R.a[p][2]), f2bf(R.a[p][3]) };
            *(u16x4*)(Ac + swz128(ar0 + 32 * p, ac4 * 8)) = pk;
        }
        #pragma unroll
        for (int p = 0; p < NB; ++p) {
            const int idx = tid + 512 * p, n = idx >> 3, c = idx & 7;
            *(u32x4*)(Bc + swz128(n, c * 16)) = R.b[p];
        }
    };
    auto compute = [&](int buf) {
        const char* Ac = (const char*)(A_lds[buf]);
        const char* Bc = (const char*)(B_lds[buf]);
        #pragma unroll
        for (int kk = 0; kk < 2; ++kk) {
            bf16x8 a[FM], b[FN];
            #pragma unroll
            for (int fm = 0; fm < FM; ++fm)
                a[fm] = *(const bf16x8*)(Ac + swz128(row_w + fm * 16 + lrow, kk * 64 + lkb));
            #pragma unroll
            for (int fn = 0; fn < FN; ++fn)
                b[fn] = *(const bf16x8*)(Bc + swz128(col_w + fn * 16 + lrow, kk * 64 + lkb));
            #pragma unroll
            for (int fm = 0; fm < FM; ++fm)
                #pragma unroll
                for (int fn = 0; fn < FN; ++fn)
                    acc[fm][fn] = __builtin_amdgcn_mfma_f32_16x16x32_bf16(a[fm], b[fn], acc[fm][fn], 0, 0, 0);
        }
    };

    // ---- prologue: tiles 0,1 issued; tile 0 staged ----
    loadG(0, R0);
    loadG(1, R1);
    storeL(0, R0);          // waits only R0's loads (R1's 6 remain outstanding)
    lbar();
    // ---- steady loop: 2 tiles per iteration, ledger in header comment ----
    for (int t = 0; t < NT; t += 2) {
        if (t + 2 < NT) loadG(t + 2, R0);
        compute(0);          // tile t (MFMA overlaps t+1/t+2 load latency)
        storeL(1, R1);       // tile t+1: counted vmcnt, not a drain
        lbar();
        if (t + 3 < NT) loadG(t + 3, R1);
        compute(1);          // tile t+1
        if (t + 2 < NT) storeL(0, R0);   // tile t+2
        lbar();
    }

    float* outp = Tpart + (size_t)ks * NNODE * NCOLS;
    #pragma unroll
    for (int fm = 0; fm < FM; ++fm) {
        const int grow0 = r0 + row_w + fm * 16 + ((lane >> 4) << 2);
        #pragma unroll
        for (int fn = 0; fn < FN; ++fn) {
            const int gcol = col_w + fn * 16 + lrow;
            #pragma unroll
            for (int j = 0; j < 4; ++j)
                outp[(size_t)(grow0 + j) * NCOLS + gcol] = acc[fm][fn][j];
        }
    }

    if (DEG) {
        __syncthreads();
        float* sc = (float*)(&A_lds[0][0]);   // 4KB scratch inside 8KB buffer
        sc[tid] = dsum0;
        sc[512 + tid] = dsum1;
        __syncthreads();
        if (tid < 64) {
            const int base = (tid < 32) ? tid * 16 : (512 + (tid - 32) * 16);
            float s = 0.f;
            #pragma unroll
            for (int i = 0; i < 16; ++i) s += sc[base + i];
            degp[(size_t)ks * NNODE + r0 + tid] = s;   // direct partial store (no atomics)
        }
    }
}

// ---------------- fused epilogue: x_e out, h1=relu (LDS), g2^T = h1@W_gc2 ----------------
template<int KSA>
__global__ __launch_bounds__(256) void post1g2(
    const float* __restrict__ tA,            // [KSA][8192][256]
    const float* __restrict__ s_src,
    const float* __restrict__ degp,          // [KSA][8192]
    const float* __restrict__ b_e,
    const float* __restrict__ b_gc1,
    const unsigned short* __restrict__ Wg2T_hi, const unsigned short* __restrict__ Wg2T_lo,
    float* __restrict__ x_e_out,
    unsigned short* __restrict__ out_t)      // B_B: [64][8192] bf16
{
    __shared__ unsigned short Hh[64 * 128], Hl[64 * 128];
    char* Hhc = (char*)Hh; char* Hlc = (char*)Hl;

    const int tid = threadIdx.x;
    const int r0 = blockIdx.x * 64;

    #pragma unroll
    for (int p = 0; p < 8; ++p) {
        int idx = tid + 256 * p, r = idx >> 5, c4 = idx & 31;
        const int gi = r0 + r;
        float dv = 0.f;
        #pragma unroll
        for (int q = 0; q < KSA; ++q) dv += degp[(size_t)q * NNODE + gi];
        f32x4 sdst = f32x4{0.f, 0.f, 0.f, 0.f}, g1 = f32x4{0.f, 0.f, 0.f, 0.f};
        #pragma unroll
        for (int q = 0; q < KSA; ++q) {
            const float* tp = tA + (size_t)q * NNODE * 256 + (size_t)gi * 256;
            f32x4 a = *(const f32x4*)(tp + c4 * 4);
            f32x4 b = *(const f32x4*)(tp + 128 + c4 * 4);
            #pragma unroll
            for (int j = 0; j < 4; ++j) { sdst[j] += a[j]; g1[j] += b[j]; }
        }
        f32x4 ss = *(const f32x4*)(s_src + (size_t)gi * 128 + c4 * 4);
        f32x4 be = *(const f32x4*)(b_e + c4 * 4);
        f32x4 bg = *(const f32x4*)(b_gc1 + c4 * 4);
        f32x4 xe;
        u16x4 ph, pl;
        #pragma unroll
        for (int j = 0; j < 4; ++j) {
            xe[j] = dv * ss[j] + sdst[j] + be[j];
            float h1 = g1[j] + bg[j];
            h1 = h1 > 0.f ? h1 : 0.f;
            unsigned short hi = f2bf(h1);
            ph[j] = hi; pl[j] = f2bf(h1 - bf2f(hi));
        }
        *(f32x4*)(x_e_out + (size_t)gi * 128 + c4 * 4) = xe;
        *(u16x4*)(Hhc + swz256(r, c4 * 8)) = ph;
        *(u16x4*)(Hlc + swz256(r, c4 * 8)) = pl;
    }
    __syncthreads();

    // g2^T = h1 @ W_gc2 : wave w covers rows w*16..+16, all 64 cols
    const int lane = tid & 63, wid = tid >> 6;
    const int lrow = lane & 15, lk8 = (lane >> 4) * 8, lkb = (lane >> 4) * 16;
    f32x4 acc[4];
    #pragma unroll
    for (int i = 0; i < 4; ++i) acc[i] = f32x4{0.f, 0.f, 0.f, 0.f};
    const int arow = wid * 16 + lrow;
    #pragma unroll
    for (int kk = 0; kk < 4; ++kk) {
        bf16x8 ah = *(const bf16x8*)(Hhc + swz256(arow, kk * 64 + lkb));
        bf16x8 al = *(const bf16x8*)(Hlc + swz256(arow, kk * 64 + lkb));
        #pragma unroll
        for (int nf = 0; nf < 4; ++nf) {
            const int n = nf * 16 + lrow;
            bf16x8 bh = *(const bf16x8*)(Wg2T_hi + (size_t)n * 128 + kk * 32 + lk8);
            bf16x8 bl = *(const bf16x8*)(Wg2T_lo + (size_t)n * 128 + kk * 32 + lk8);
            acc[nf] = __builtin_amdgcn_mfma_f32_16x16x32_bf16(ah, bh, acc[nf], 0, 0, 0);
            acc[nf] = __builtin_amdgcn_mfma_f32_16x16x32_bf16(ah, bl, acc[nf], 0, 0, 0);
            acc[nf] = __builtin_amdgcn_mfma_f32_16x16x32_bf16(al, bh, acc[nf], 0, 0, 0);
        }
    }
    const int rowb = r0 + wid * 16 + ((lane >> 4) << 2);
    #pragma unroll
    for (int nf = 0; nf < 4; ++nf) {
        const int col = nf * 16 + lrow;
        u16x4 pk = { f2bf(acc[nf][0]), f2bf(acc[nf][1]), f2bf(acc[nf][2]), f2bf(acc[nf][3]) };
        *(u16x4*)(out_t + (size_t)col * NNODE + rowb) = pk;
    }
}

// ---------------- log_softmax over 40 classes, one wave per row ----------------
template<int KSPLIT>
__global__ void logsm(const float* __restrict__ tB,     // [KSPLIT][8192][64]
                      const float* __restrict__ b_gc2,
                      float* __restrict__ out)
{
    const int wid = threadIdx.x >> 6, lane = threadIdx.x & 63;
    const int row = blockIdx.x * 4 + wid;
    float v = -1e30f;
    if (lane < 40) {
        float s = b_gc2[lane];
        #pragma unroll
        for (int p = 0; p < KSPLIT; ++p)
            s += tB[(size_t)p * NNODE * 64 + (size_t)row * 64 + lane];
        v = s;
    }
    float m = v;
    #pragma unroll
    for (int off = 32; off; off >>= 1) m = fmaxf(m, __shfl_xor(m, off, 64));
    float e = (lane < 40) ? expf(v - m) : 0.f;
    float s = e;
    #pragma unroll
    for (int off = 32; off; off >>= 1) s += __shfl_xor(s, off, 64);
    if (lane < 40) out[(size_t)row * 40 + lane] = v - m - logf(s);
}

extern "C" void kernel_launch(void* const* d_in, const int* in_sizes, int n_in,
                              void* d_out, int out_size, void* d_ws, size_t ws_size,
                              hipStream_t stream)
{
    const float* x     = (const float*)d_in[0];
    const float* adj   = (const float*)d_in[1];
    const float* W_emb = (const float*)d_in[2];
    const float* b_emb = (const float*)d_in[3];
    const float* W_gc1 = (const float*)d_in[4];
    const float* b_gc1 = (const float*)d_in[5];
    const float* W_e   = (const float*)d_in[6];
    const float* b_e   = (const float*)d_in[7];
    const float* W_gc2 = (const float*)d_in[8];
    const float* b_gc2 = (const float*)d_in[9];

    constexpr int KSA = 2;
    constexpr int KSB = 2;

    char* p = (char*)d_ws;
    auto take = [&](size_t bytes) { char* q = p; p += (bytes + 255) & ~(size_t)255; return q; };

    unsigned short* WembT_hi = (unsigned short*)take(128 * 128 * 2);
    unsigned short* WembT_lo = (unsigned short*)take(128 * 128 * 2);
    unsigned short* WcatT_hi = (unsigned short*)take(384 * 128 * 2);
    unsigned short* WcatT_lo = (unsigned short*)take(384 * 128 * 2);
    unsigned short* Wg2T_hi  = (unsigned short*)take(64 * 128 * 2);
    unsigned short* Wg2T_lo  = (unsigned short*)take(64 * 128 * 2);
    float*          s_src    = (float*)take((size_t)NNODE * 128 * 4);
    unsigned short* B_A      = (unsigned short*)take((size_t)256 * NNODE * 2);
    unsigned short* B_B      = (unsigned short*)take((size_t)64 * NNODE * 2);
    float*          tA       = (float*)take((size_t)KSA * NNODE * 256 * 4);
    float*          tB       = (float*)take((size_t)KSB * NNODE * 64 * 4);
    float*          degp     = (float*)take((size_t)KSA * NNODE * 4);

    float* out_ls = (float*)d_out;                       // [8192][40]
    float* x_e    = (float*)d_out + (size_t)NNODE * 40;  // [8192][128]

    prep_w<<<288, 256, 0, stream>>>(W_emb, W_e, W_gc1, W_gc2,
                                    WembT_hi, WembT_lo, WcatT_hi, WcatT_lo, Wg2T_hi, Wg2T_lo);
    // h = x@W_emb+b_emb ; [s_src | s_dst^T | g1^T] = h@W_cat   (fused, h in LDS)
    gemm_hs<<<128, 512, 0, stream>>>(x, WembT_hi, WembT_lo, WcatT_hi, WcatT_lo, b_emb,
                                     s_src, B_A);
    // pass A: tA = adj @ [s_dst | g1], degp = partial row sums
    adj_gemm<256, KSA, true, false><<<dim3(128, KSA), 512, 0, stream>>>(adj, B_A, tA, degp);
    // x_e out, h1 = relu(...) in LDS, g2^T = h1@W_gc2   (fused)
    post1g2<KSA><<<128, 256, 0, stream>>>(tA, s_src, degp, b_e, b_gc1,
                                          Wg2T_hi, Wg2T_lo, x_e, B_B);
    // pass B: tB = adj @ g2 (reverse-K for L3 recency)
    adj_gemm<64, KSB, false, true><<<dim3(128, KSB), 512, 0, stream>>>(adj, B_B, tB, nullptr);
    // log_softmax(+b_gc2) -> out
    logsm<KSB><<<2048, 256, 0, stream>>>(tB, b_gc2, out_ls);
}